// Round 10
// baseline (148.519 us; speedup 1.0000x reference)
//
#include <hip/hip_runtime.h>
#include <hip/hip_bf16.h>
#include <math.h>

// B=4, N=2048, C=768, H=12, D=64; tokens = 8192

typedef short bf16x8 __attribute__((ext_vector_type(8)));
typedef float f32x4 __attribute__((ext_vector_type(4)));
typedef float f32x16 __attribute__((ext_vector_type(16)));

static __device__ __forceinline__ unsigned short f2bf(float f) {
    unsigned int u = __float_as_uint(f);
    unsigned int r = u + 0x7fff + ((u >> 16) & 1);   // RNE
    return (unsigned short)(r >> 16);
}
static __device__ __forceinline__ unsigned int pack2(float a, float b) {
    return (unsigned int)f2bf(a) | ((unsigned int)f2bf(b) << 16);
}
// HW packed f32x2 -> bf16x2 (RNE), single VALU op
static __device__ __forceinline__ unsigned int cvtpk(float a, float b) {
    unsigned int r;
    asm("v_cvt_pk_bf16_f32 %0, %1, %2" : "=v"(r) : "v"(a), "v"(b));
    return r;
}
static __device__ __forceinline__ void gl_lds16(const void* g, void* l) {
    __builtin_amdgcn_global_load_lds(
        (const __attribute__((address_space(1))) unsigned int*)g,
        (__attribute__((address_space(3))) unsigned int*)l, 16, 0, 0);
}

// ---------------- converter: x fp32 -> bf16 ----------------
__global__ __launch_bounds__(256) void convx_kernel(
    const float* __restrict__ in, unsigned short* __restrict__ out)
{
    size_t i = ((size_t)blockIdx.x * 256 + threadIdx.x) * 8;
    float4 a = *(const float4*)&in[i];
    float4 b = *(const float4*)&in[i + 4];
    uint4 o = make_uint4(pack2(a.x, a.y), pack2(a.z, a.w), pack2(b.x, b.y), pack2(b.z, b.w));
    *(uint4*)&out[i] = o;
}

// ---------------- converter: transpose fp32 weights -> bf16 [cols][768], both W sets ----
// grid (48, 12): x<36 -> [Wq|Wkv] -> WqkvT (2304x768); x>=36 -> Wp -> WprjT (768x768)
__global__ __launch_bounds__(256) void convT_kernel(
    const float* __restrict__ Wq, const float* __restrict__ Wkv, const float* __restrict__ Wp,
    unsigned short* __restrict__ WqkvT, unsigned short* __restrict__ WprjT)
{
    __shared__ char tb[8192];
    const int bx = blockIdx.x, k0 = blockIdx.y * 64;
    const float* src; int ld; int cbase; unsigned short* out; int c0;
    if (bx < 36) {
        c0 = bx * 64; out = WqkvT;
        if (c0 < 768) { src = Wq;  ld = 768;  cbase = c0; }
        else          { src = Wkv; ld = 1536; cbase = c0 - 768; }
    } else {
        c0 = (bx - 36) * 64; out = WprjT; src = Wp; ld = 768; cbase = c0;
    }
    const int t = threadIdx.x;
    const int kl = t >> 2, cq = (t & 3) * 16;
    #pragma unroll
    for (int jj = 0; jj < 4; ++jj) {
        float4 v = *(const float4*)&src[(size_t)(k0 + kl) * ld + cbase + cq + jj * 4];
        float vv[4] = {v.x, v.y, v.z, v.w};
        #pragma unroll
        for (int je = 0; je < 4; ++je) {
            int c = cq + jj * 4 + je;
            *(unsigned short*)(tb + c * 128 + ((kl * 2) ^ ((c & 7) << 4))) = f2bf(vv[je]);
        }
    }
    __syncthreads();
    const int cl = t >> 2, u2 = (t & 3) * 2;
    uint4 r0 = *(const uint4*)(tb + cl * 128 + ((u2 ^ (cl & 7)) << 4));
    uint4 r1 = *(const uint4*)(tb + cl * 128 + (((u2 + 1) ^ (cl & 7)) << 4));
    size_t ob = (size_t)(c0 + cl) * 768 + k0 + (t & 3) * 16;
    *(uint4*)&out[ob] = r0;
    *(uint4*)&out[ob + 8] = r1;
}

// ---------------- Kernel: QKV bf16 MFMA GEMM + bias + l2norm + scatter ----------------
// Q is pre-scaled by scale*log2(e) so attention can use raw exp2.
__global__ __launch_bounds__(256) void qkv_gemm_kernel(
    const unsigned short* __restrict__ xb, const unsigned short* __restrict__ WT,
    const float* __restrict__ bq, const float* __restrict__ bkv,
    const float* __restrict__ scale,
    unsigned short* __restrict__ Qb, unsigned short* __restrict__ Kb,
    unsigned short* __restrict__ Vtb)
{
    __shared__ char lds[32768] __attribute__((aligned(16)));

    const int ct = blockIdx.x;
    const int row0 = blockIdx.y * 128;
    const int tid = threadIdx.x;
    const int w = tid >> 6, l = tid & 63;
    const int g = l >> 4, ln = l & 15;
    const int wr = w >> 1, wc = w & 1;
    const int col0 = ct * 128;

    const int srow = (w & 1) * 64 + (l >> 3);
    const int su = ((l & 7) ^ (l >> 3)) * 16;
    const char* s = (w < 2)
        ? (const char*)xb + (size_t)(row0 + srow) * 1536 + su
        : (const char*)WT + (size_t)(col0 + srow) * 1536 + su;
    char* dbase = lds + ((w >= 2) ? 16384 : 0) + (w & 1) * 8192;

    f32x4 acc[4][4];
    #pragma unroll
    for (int m = 0; m < 4; ++m)
        #pragma unroll
        for (int n = 0; n < 4; ++n) acc[m][n] = (f32x4){0.f, 0.f, 0.f, 0.f};

    const int arow = (wr * 64 + ln) * 128;
    const int brow = 16384 + (wc * 64 + ln) * 128;
    const int x0 = ((0 + g) ^ (ln & 7)) * 16;
    const int x1 = ((4 + g) ^ (ln & 7)) * 16;

    for (int ks = 0; ks < 12; ++ks) {
        __syncthreads();
        #pragma unroll
        for (int j = 0; j < 8; ++j)
            gl_lds16(s + (size_t)j * 8 * 1536, dbase + j * 1024);
        s += 128;
        __syncthreads();
        #pragma unroll
        for (int kc = 0; kc < 2; ++kc) {
            const int xo = kc ? x1 : x0;
            bf16x8 af[4], bfr[4];
            #pragma unroll
            for (int m = 0; m < 4; ++m) af[m] = *(const bf16x8*)(lds + arow + m * 2048 + xo);
            #pragma unroll
            for (int n = 0; n < 4; ++n) bfr[n] = *(const bf16x8*)(lds + brow + n * 2048 + xo);
            #pragma unroll
            for (int m = 0; m < 4; ++m)
                #pragma unroll
                for (int n = 0; n < 4; ++n)
                    acc[m][n] = __builtin_amdgcn_mfma_f32_16x16x32_bf16(af[m], bfr[n], acc[m][n], 0, 0, 0);
        }
    }

    const int co = col0 + wc * 64 + ln;
    float bv[4];
    #pragma unroll
    for (int n = 0; n < 4; ++n) {
        int c = co + n * 16;
        bv[n] = (c < 768) ? bq[c] : bkv[c - 768];
    }
    const int region = ct / 6;
    const int h = (ct % 6) * 2 + wc;

    if (region < 2) {
        unsigned short* dst = (region == 0) ? Qb : Kb;
        const float post = (region == 0) ? scale[0] * 1.4426950408889634f : 1.0f;
        #pragma unroll
        for (int m = 0; m < 4; ++m) {
            #pragma unroll
            for (int n = 0; n < 4; ++n)
                #pragma unroll
                for (int r = 0; r < 4; ++r) acc[m][n][r] += bv[n];
            #pragma unroll
            for (int r = 0; r < 4; ++r) {
                float ss = 0.f;
                #pragma unroll
                for (int n = 0; n < 4; ++n) ss += acc[m][n][r] * acc[m][n][r];
                ss += __shfl_xor(ss, 1); ss += __shfl_xor(ss, 2);
                ss += __shfl_xor(ss, 4); ss += __shfl_xor(ss, 8);
                float inv = post / fmaxf(sqrtf(ss), 1e-12f);
                int t = row0 + wr * 64 + m * 16 + g * 4 + r;
                int b = t >> 11, nt = t & 2047;
                size_t base = ((size_t)(b * 12 + h) * 2048 + nt) * 64 + ln;
                #pragma unroll
                for (int n = 0; n < 4; ++n)
                    dst[base + n * 16] = f2bf(acc[m][n][r] * inv);
            }
        }
    } else {
        char* tb = lds + w * 8192;
        __syncthreads();
        #pragma unroll
        for (int m = 0; m < 4; ++m)
            #pragma unroll
            for (int n = 0; n < 4; ++n)
                #pragma unroll
                for (int r = 0; r < 4; ++r) {
                    int d = n * 16 + ln;
                    int tok = m * 16 + g * 4 + r;
                    *(unsigned short*)(tb + d * 128 + ((tok * 2) ^ ((d & 7) << 4))) =
                        f2bf(acc[m][n][r] + bv[n]);
                }
        __syncthreads();
        const int t0 = row0 + wr * 64;
        const int b = t0 >> 11, n0 = t0 & 2047;
        #pragma unroll
        for (int i = 0; i < 8; ++i) {
            int d = i * 8 + (l >> 3);
            uint4 v = *(const uint4*)(tb + d * 128 + (((l & 7) ^ (d & 7)) << 4));
            *(uint4*)&Vtb[((size_t)(b * 12 + h) * 64 + d) * 2048 + n0 + (l & 7) * 8] = v;
        }
    }
}

// ---------------- Kernel: MFMA flash attention, 2 waves x 64 q-rows, K/V frags shared ----
// grid (16, 48) XCD-remapped, block 128 = 2 waves, KT=64. MFMA:ds_read = 2:1.
__global__ __launch_bounds__(128, 2) void attn_kernel(
    const unsigned short* __restrict__ Qg, const unsigned short* __restrict__ Kg,
    const unsigned short* __restrict__ Vtg,
    unsigned short* __restrict__ O)
{
    __shared__ char lds[32768] __attribute__((aligned(16)));
    // K dbuf: 0/8192 ; Vt dbuf: 16384/24576

    const int bid = blockIdx.y * 16 + blockIdx.x;
    const int swzb = (bid & 7) * 96 + (bid >> 3);
    const int bh = swzb >> 4;
    const int q0 = (swzb & 15) * 128;

    const int tid = threadIdx.x;
    const int w  = tid >> 6;          // 0..1
    const int l  = tid & 63;
    const int lo = l & 31;
    const int hi = l >> 5;

    // staging (pre-swizzled source): wave w stages rows w*32..w*32+31 (4 chunks of 8 rows)
    const int srow = w * 32 + (l >> 3);
    const int su   = ((l & 7) ^ (l >> 3)) * 16;
    const char* kS = (const char*)Kg  + ((size_t)bh * 2048 + srow) * 128 + su;   // +t*8192
    const char* vS = (const char*)Vtg + ((size_t)bh * 64   + srow) * 4096 + su;  // +t*128
    char* kD = lds + w * 4096;
    char* vD = lds + 16384 + w * 4096;

    auto stage = [&](int t, int buf) {
        const char* pk = kS + (size_t)t * 8192;
        const char* pv = vS + (size_t)t * 128;
        char* dk = kD + buf * 8192;
        char* dv = vD + buf * 8192;
        #pragma unroll
        for (int i = 0; i < 4; ++i) {
            gl_lds16(pk + i * 1024, dk + i * 1024);
            gl_lds16(pv + (size_t)i * 32768, dv + i * 1024);
        }
    };

    // Q B-frags: qblock A = rows q0+w*64..+31, qblock B = +32
    bf16x8 qfA[4], qfB[4];
    {
        const unsigned short* qp = Qg + ((size_t)bh * 2048 + q0 + w * 64 + lo) * 64 + hi * 8;
        #pragma unroll
        for (int c = 0; c < 4; ++c) {
            qfA[c] = *(const bf16x8*)(qp + c * 16);
            qfB[c] = *(const bf16x8*)(qp + 2048 + c * 16);
        }
    }

    const int swz = (lo & 7) << 4;
    const int rowb = lo * 128;
    int coff[4];
    #pragma unroll
    for (int c = 0; c < 4; ++c) coff[c] = (c * 32 + hi * 16) ^ swz;

    f32x16 oA0, oA1, oB0, oB1;
    #pragma unroll
    for (int r = 0; r < 16; ++r) { oA0[r] = 0.f; oA1[r] = 0.f; oB0[r] = 0.f; oB1[r] = 0.f; }
    float rsA = 0.f, rsB = 0.f;

    const f32x16 zero16 = {0.f,0.f,0.f,0.f,0.f,0.f,0.f,0.f,0.f,0.f,0.f,0.f,0.f,0.f,0.f,0.f};

    auto compute = [&](const int OFF) {
        const char* Kb = lds + OFF;
        const char* Vb = lds + 16384 + OFF;

        // ---- shared K fragments (rows 0-31 and 32-63) ----
        bf16x8 kf[4], kg2[4];
        #pragma unroll
        for (int c = 0; c < 4; ++c) {
            kf[c]  = *(const bf16x8*)(Kb + rowb + coff[c]);
            kg2[c] = *(const bf16x8*)(Kb + 4096 + rowb + coff[c]);
        }

        // ---- S^T = K Q^T for both q-blocks (K frags reused) ----
        f32x16 sA0, sA1, sB0, sB1;
        __builtin_amdgcn_s_setprio(1);
        sA0 = __builtin_amdgcn_mfma_f32_32x32x16_bf16(kf[0], qfA[0], zero16, 0, 0, 0);
        sA0 = __builtin_amdgcn_mfma_f32_32x32x16_bf16(kf[1], qfA[1], sA0, 0, 0, 0);
        sA0 = __builtin_amdgcn_mfma_f32_32x32x16_bf16(kf[2], qfA[2], sA0, 0, 0, 0);
        sA0 = __builtin_amdgcn_mfma_f32_32x32x16_bf16(kf[3], qfA[3], sA0, 0, 0, 0);
        sA1 = __builtin_amdgcn_mfma_f32_32x32x16_bf16(kg2[0], qfA[0], zero16, 0, 0, 0);
        sA1 = __builtin_amdgcn_mfma_f32_32x32x16_bf16(kg2[1], qfA[1], sA1, 0, 0, 0);
        sA1 = __builtin_amdgcn_mfma_f32_32x32x16_bf16(kg2[2], qfA[2], sA1, 0, 0, 0);
        sA1 = __builtin_amdgcn_mfma_f32_32x32x16_bf16(kg2[3], qfA[3], sA1, 0, 0, 0);
        sB0 = __builtin_amdgcn_mfma_f32_32x32x16_bf16(kf[0], qfB[0], zero16, 0, 0, 0);
        sB0 = __builtin_amdgcn_mfma_f32_32x32x16_bf16(kf[1], qfB[1], sB0, 0, 0, 0);
        sB0 = __builtin_amdgcn_mfma_f32_32x32x16_bf16(kf[2], qfB[2], sB0, 0, 0, 0);
        sB0 = __builtin_amdgcn_mfma_f32_32x32x16_bf16(kf[3], qfB[3], sB0, 0, 0, 0);
        sB1 = __builtin_amdgcn_mfma_f32_32x32x16_bf16(kg2[0], qfB[0], zero16, 0, 0, 0);
        sB1 = __builtin_amdgcn_mfma_f32_32x32x16_bf16(kg2[1], qfB[1], sB1, 0, 0, 0);
        sB1 = __builtin_amdgcn_mfma_f32_32x32x16_bf16(kg2[2], qfB[2], sB1, 0, 0, 0);
        sB1 = __builtin_amdgcn_mfma_f32_32x32x16_bf16(kg2[3], qfB[3], sB1, 0, 0, 0);
        __builtin_amdgcn_s_setprio(0);

        // ---- exp2 + row-sum + cvt_pk (verified R8/R9 mapping) ----
        unsigned int pA[16], pB[16];
        #pragma unroll
        for (int kb = 0; kb < 2; ++kb) {
            float e[16];
            #pragma unroll
            for (int r = 0; r < 16; ++r)
                e[r] = __builtin_amdgcn_exp2f(kb ? sA1[r] : sA0[r]);
            float t = 0.f;
            #pragma unroll
            for (int r = 0; r < 16; r += 4) t += (e[r] + e[r+1]) + (e[r+2] + e[r+3]);
            rsA += t;
            #pragma unroll
            for (int ksb = 0; ksb < 2; ++ksb) {
                pA[kb*8 + ksb*4 + 0] = cvtpk(e[ksb*8 + 0], e[ksb*8 + 1]);
                pA[kb*8 + ksb*4 + 1] = cvtpk(e[ksb*8 + 2], e[ksb*8 + 3]);
                pA[kb*8 + ksb*4 + 2] = cvtpk(e[ksb*8 + 4], e[ksb*8 + 5]);
                pA[kb*8 + ksb*4 + 3] = cvtpk(e[ksb*8 + 6], e[ksb*8 + 7]);
            }
        }
        #pragma unroll
        for (int kb = 0; kb < 2; ++kb) {
            float e[16];
            #pragma unroll
            for (int r = 0; r < 16; ++r)
                e[r] = __builtin_amdgcn_exp2f(kb ? sB1[r] : sB0[r]);
            float t = 0.f;
            #pragma unroll
            for (int r = 0; r < 16; r += 4) t += (e[r] + e[r+1]) + (e[r+2] + e[r+3]);
            rsB += t;
            #pragma unroll
            for (int ksb = 0; ksb < 2; ++ksb) {
                pB[kb*8 + ksb*4 + 0] = cvtpk(e[ksb*8 + 0], e[ksb*8 + 1]);
                pB[kb*8 + ksb*4 + 1] = cvtpk(e[ksb*8 + 2], e[ksb*8 + 3]);
                pB[kb*8 + ksb*4 + 2] = cvtpk(e[ksb*8 + 4], e[ksb*8 + 5]);
                pB[kb*8 + ksb*4 + 3] = cvtpk(e[ksb*8 + 6], e[ksb*8 + 7]);
            }
        }

        // ---- PV: V fragments shared between q-blocks ----
        #pragma unroll
        for (int kb = 0; kb < 2; ++kb) {
            #pragma unroll
            for (int ksb = 0; ksb < 2; ++ksb) {
                const int base = kb*8 + ksb*4;
                const int ks = kb*2 + ksb;
                bf16x8 v0 = *(const bf16x8*)(Vb + rowb + coff[ks]);
                bf16x8 v1 = *(const bf16x8*)(Vb + 4096 + rowb + coff[ks]);
                unsigned int a0 = pA[base], a1 = pA[base+1], a2 = pA[base+2], a3 = pA[base+3];
                asm("v_permlane32_swap_b32 %0, %1" : "+v"(a0), "+v"(a2));
                asm("v_permlane32_swap_b32 %0, %1" : "+v"(a1), "+v"(a3));
                unsigned int fwA[4] = {a0, a1, a2, a3};
                bf16x8 paA; __builtin_memcpy(&paA, fwA, 16);
                unsigned int b0 = pB[base], b1 = pB[base+1], b2 = pB[base+2], b3 = pB[base+3];
                asm("v_permlane32_swap_b32 %0, %1" : "+v"(b0), "+v"(b2));
                asm("v_permlane32_swap_b32 %0, %1" : "+v"(b1), "+v"(b3));
                unsigned int fwB[4] = {b0, b1, b2, b3};
                bf16x8 paB; __builtin_memcpy(&paB, fwB, 16);
                __builtin_amdgcn_s_setprio(1);
                oA0 = __builtin_amdgcn_mfma_f32_32x32x16_bf16(paA, v0, oA0, 0, 0, 0);
                oA1 = __builtin_amdgcn_mfma_f32_32x32x16_bf16(paA, v1, oA1, 0, 0, 0);
                oB0 = __builtin_amdgcn_mfma_f32_32x32x16_bf16(paB, v0, oB0, 0, 0, 0);
                oB1 = __builtin_amdgcn_mfma_f32_32x32x16_bf16(paB, v1, oB1, 0, 0, 0);
                __builtin_amdgcn_s_setprio(0);
            }
        }
    };

    // prologue: tile 0 -> buf0
    stage(0, 0);
    __syncthreads();

    #pragma unroll 1
    for (int it = 0; it < 16; ++it) {
        stage(2 * it + 1, 1);
        compute(0);
        __syncthreads();
        if (it < 15) stage(2 * it + 2, 0);
        compute(8192);
        __syncthreads();
    }

    // epilogue: reduce row-sums, normalize, store bf16 token-major
    float vA = rsA; vA += __shfl_xor(vA, 32);
    float vB = rsB; vB += __shfl_xor(vB, 32);
    const int b = bh / 12, h = bh % 12;
    #pragma unroll
    for (int r = 0; r < 16; ++r) {
        const int qr = (r & 3) + 8 * (r >> 2) + 4 * hi;
        float invA = 1.0f / __shfl(vA, qr);
        float invB = 1.0f / __shfl(vB, qr);
        size_t baseA = ((size_t)(b * 2048 + q0 + w * 64 + qr)) * 768 + h * 64 + lo;
        O[baseA]      = f2bf(oA0[r] * invA);
        O[baseA + 32] = f2bf(oA1[r] * invA);
        size_t baseB = baseA + (size_t)32 * 768;
        O[baseB]      = f2bf(oB0[r] * invB);
        O[baseB + 32] = f2bf(oB1[r] * invB);
    }
}

// ---------------- Kernel: proj bf16 MFMA GEMM + bias -> fp32 out ----------------
__global__ __launch_bounds__(256) void proj_gemm_kernel(
    const unsigned short* __restrict__ Ob, const unsigned short* __restrict__ WT,
    const float* __restrict__ bp, float* __restrict__ out)
{
    __shared__ char lds[32768] __attribute__((aligned(16)));

    const int row0 = blockIdx.y * 128;
    const int col0 = blockIdx.x * 128;
    const int tid = threadIdx.x;
    const int w = tid >> 6, l = tid & 63;
    const int g = l >> 4, ln = l & 15;
    const int wr = w >> 1, wc = w & 1;

    const int srow = (w & 1) * 64 + (l >> 3);
    const int su = ((l & 7) ^ (l >> 3)) * 16;
    const char* s = (w < 2)
        ? (const char*)Ob + (size_t)(row0 + srow) * 1536 + su
        : (const char*)WT + (size_t)(col0 + srow) * 1536 + su;
    char* dbase = lds + ((w >= 2) ? 16384 : 0) + (w & 1) * 8192;

    f32x4 acc[4][4];
    #pragma unroll
    for (int m = 0; m < 4; ++m)
        #pragma unroll
        for (int n = 0; n < 4; ++n) acc[m][n] = (f32x4){0.f, 0.f, 0.f, 0.f};

    const int arow = (wr * 64 + ln) * 128;
    const int brow = 16384 + (wc * 64 + ln) * 128;
    const int x0 = ((0 + g) ^ (ln & 7)) * 16;
    const int x1 = ((4 + g) ^ (ln & 7)) * 16;

    for (int ks = 0; ks < 12; ++ks) {
        __syncthreads();
        #pragma unroll
        for (int j = 0; j < 8; ++j)
            gl_lds16(s + (size_t)j * 8 * 1536, dbase + j * 1024);
        s += 128;
        __syncthreads();
        #pragma unroll
        for (int kc = 0; kc < 2; ++kc) {
            const int xo = kc ? x1 : x0;
            bf16x8 af[4], bfr[4];
            #pragma unroll
            for (int m = 0; m < 4; ++m) af[m] = *(const bf16x8*)(lds + arow + m * 2048 + xo);
            #pragma unroll
            for (int n = 0; n < 4; ++n) bfr[n] = *(const bf16x8*)(lds + brow + n * 2048 + xo);
            #pragma unroll
            for (int m = 0; m < 4; ++m)
                #pragma unroll
                for (int n = 0; n < 4; ++n)
                    acc[m][n] = __builtin_amdgcn_mfma_f32_16x16x32_bf16(af[m], bfr[n], acc[m][n], 0, 0, 0);
        }
    }

    const int co = col0 + wc * 64 + ln;
    float bv[4];
    #pragma unroll
    for (int n = 0; n < 4; ++n) bv[n] = bp[co + n * 16];
    #pragma unroll
    for (int m = 0; m < 4; ++m)
        #pragma unroll
        for (int r = 0; r < 4; ++r) {
            int t = row0 + wr * 64 + m * 16 + g * 4 + r;
            #pragma unroll
            for (int n = 0; n < 4; ++n)
                out[(size_t)t * 768 + co + n * 16] = acc[m][n][r] + bv[n];
        }
}

extern "C" void kernel_launch(void* const* d_in, const int* in_sizes, int n_in,
                              void* d_out, int out_size, void* d_ws, size_t ws_size,
                              hipStream_t stream) {
    const float* x     = (const float*)d_in[0];
    const float* Wq    = (const float*)d_in[1];
    const float* bq    = (const float*)d_in[2];
    const float* Wkv   = (const float*)d_in[3];
    const float* bkv   = (const float*)d_in[4];
    const float* Wp    = (const float*)d_in[5];
    const float* bp    = (const float*)d_in[6];
    const float* scale = (const float*)d_in[7];
    float* out = (float*)d_out;

    unsigned short* ws = (unsigned short*)d_ws;
    const size_t SZ = (size_t)4 * 12 * 2048 * 64;     // 6,291,456
    unsigned short* xbw   = ws;
    unsigned short* WqkvT = xbw + SZ;
    unsigned short* WprjT = WqkvT + (size_t)2304 * 768;
    unsigned short* Qw    = WprjT + (size_t)768 * 768;
    unsigned short* Kw    = Qw + SZ;
    unsigned short* Vtw   = Kw + SZ;
    unsigned short* Ow    = Vtw + SZ;

    convx_kernel<<<3072, 256, 0, stream>>>(x, xbw);
    convT_kernel<<<dim3(48, 12), 256, 0, stream>>>(Wq, Wkv, Wp, WqkvT, WprjT);
    qkv_gemm_kernel<<<dim3(18, 64), 256, 0, stream>>>(xbw, WqkvT, bq, bkv, scale, Qw, Kw, Vtw);
    attn_kernel<<<dim3(16, 48), 128, 0, stream>>>(Qw, Kw, Vtw, Ow);
    proj_gemm_kernel<<<dim3(6, 64), 256, 0, stream>>>(Ow, WprjT, bp, out);
}